// Round 1
// baseline (118.272 us; speedup 1.0000x reference)
//
#include <hip/hip_runtime.h>
#include <math.h>

#define NF 7
#define NR 128
#define ROWS_PER_BLOCK 8

__global__ __launch_bounds__(256) void anfis_kernel(
    const float* __restrict__ x,
    const float* __restrict__ mu_g,
    const float* __restrict__ sig_g,
    const float* __restrict__ ta, const float* __restrict__ tb,
    const float* __restrict__ tc, const float* __restrict__ td,
    const float* __restrict__ mf_mix,
    const float* __restrict__ tnw,
    const float* __restrict__ consequent,   // [128][8]
    const int*   __restrict__ rule_idx,     // [128][7]
    float* __restrict__ out,                // [B]
    float* __restrict__ nf_out,             // [B][128]
    float* __restrict__ mem_out,            // [B][14]
    int nrows)
{
    __shared__ float s_xaug[ROWS_PER_BLOCK][8];    // [1, x0..x6]
    __shared__ float s_mem[ROWS_PER_BLOCK][16];    // 14 used, padded
    __shared__ unsigned int s_mask32[32];          // 128 rule masks, packed 4/word

    const int tid = threadIdx.x;
    const int row_local = tid >> 5;                // 0..7
    const int j = tid & 31;                        // lane within row-group
    const int row = blockIdx.x * ROWS_PER_BLOCK + row_local;
    const bool live = (row < nrows);

    // ---- phase 0: rule masks (block-wide) + x staging ----
    if (tid < NR) {
        int m = 0;
        #pragma unroll
        for (int i = 0; i < NF; ++i)
            if (rule_idx[tid * NF + i] != 0) m |= (1 << i);
        ((unsigned char*)s_mask32)[tid] = (unsigned char)m;
    }
    if (j < NF) s_xaug[row_local][1 + j] = live ? x[row * NF + j] : 0.0f;
    if (j == NF) s_xaug[row_local][0] = 1.0f;

    const float alpha = 1.0f / (1.0f + __expf(-mf_mix[0]));
    const float w     = 1.0f / (1.0f + __expf(-tnw[0]));
    __syncthreads();

    // ---- phase 1: 14 membership values per row ----
    if (j < 14) {
        const int i = j >> 1;                      // feature
        const float xi = s_xaug[row_local][1 + i];
        float sg = sig_g[j];
        sg = fmaxf(sg, 1e-6f);
        const float dm = xi - mu_g[j];
        const float gauss = __expf(-(dm * dm) / (2.0f * sg * sg));

        float p0 = ta[j], p1 = tb[j], p2 = tc[j], p3 = td[j];
        float lo, hi;
        lo = fminf(p0, p1); hi = fmaxf(p0, p1); p0 = lo; p1 = hi;
        lo = fminf(p2, p3); hi = fmaxf(p2, p3); p2 = lo; p3 = hi;
        lo = fminf(p0, p2); hi = fmaxf(p0, p2); p0 = lo; p2 = hi;
        lo = fminf(p1, p3); hi = fmaxf(p1, p3); p1 = lo; p3 = hi;
        lo = fminf(p1, p2); hi = fmaxf(p1, p2); p1 = lo; p2 = hi;

        float left  = (xi - p0) / (p1 - p0 + 1e-6f);
        left = fminf(fmaxf(left, 0.0f), 1.0f);
        const float flat = (xi >= p1 && xi <= p2) ? 1.0f : 0.0f;
        float right = (p3 - xi) / (p3 - p2 + 1e-6f);
        right = fminf(fmaxf(right, 0.0f), 1.0f);
        const float trap = fmaxf(fminf(left, right), flat);

        const float m = alpha * gauss + (1.0f - alpha) * trap;
        s_mem[row_local][j] = m;
        if (live) mem_out[row * 14 + j] = m;
    }
    __syncthreads();

    // ---- phase 2: 4 rules per thread ----
    const float4 xa0 = *(const float4*)&s_xaug[row_local][0];
    const float4 xa1 = *(const float4*)&s_xaug[row_local][4];
    const float4 mA = *(const float4*)&s_mem[row_local][0];
    const float4 mB = *(const float4*)&s_mem[row_local][4];
    const float4 mC = *(const float4*)&s_mem[row_local][8];
    const float  mD0 = s_mem[row_local][12];
    const float  mD1 = s_mem[row_local][13];

    float mlo[NF], mhi[NF];
    mlo[0] = mA.x; mhi[0] = mA.y;
    mlo[1] = mA.z; mhi[1] = mA.w;
    mlo[2] = mB.x; mhi[2] = mB.y;
    mlo[3] = mB.z; mhi[3] = mB.w;
    mlo[4] = mC.x; mhi[4] = mC.y;
    mlo[5] = mC.z; mhi[5] = mC.w;
    mlo[6] = mD0;  mhi[6] = mD1;

    const unsigned int pk = s_mask32[j];
    const float4* __restrict__ cq = (const float4*)consequent;

    float f[4];
    float S = 0.0f, dot = 0.0f;
    const int r0 = 4 * j;

    #pragma unroll
    for (int k = 0; k < 4; ++k) {
        const unsigned int msk = (pk >> (8 * k)) & 0xffu;
        float g[NF];
        #pragma unroll
        for (int i = 0; i < NF; ++i)
            g[i] = ((msk >> i) & 1u) ? mhi[i] : mlo[i];

        const float prod = ((g[0] * g[1]) * (g[2] * g[3])) *
                           ((g[4] * g[5]) * g[6]);
        const float mn = fminf(fminf(fminf(g[0], g[1]), fminf(g[2], g[3])),
                               fminf(fminf(g[4], g[5]), g[6]));
        const float fr = w * prod + (1.0f - w) * mn;

        const int r = r0 + k;
        const float4 c0 = cq[2 * r];
        const float4 c1 = cq[2 * r + 1];
        float ro = c0.x * xa0.x;
        ro = fmaf(c0.y, xa0.y, ro);
        ro = fmaf(c0.z, xa0.z, ro);
        ro = fmaf(c0.w, xa0.w, ro);
        ro = fmaf(c1.x, xa1.x, ro);
        ro = fmaf(c1.y, xa1.y, ro);
        ro = fmaf(c1.z, xa1.z, ro);
        ro = fmaf(c1.w, xa1.w, ro);

        f[k] = fr;
        S += fr;
        dot = fmaf(fr, ro, dot);
    }

    // ---- phase 3: reduce over the 32-lane row-group ----
    #pragma unroll
    for (int off = 1; off < 32; off <<= 1) {
        S   += __shfl_xor(S, off, 64);
        dot += __shfl_xor(dot, off, 64);
    }
    const float invS = 1.0f / (S + 1e-8f);

    if (live) {
        float4 nf4;
        nf4.x = f[0] * invS;
        nf4.y = f[1] * invS;
        nf4.z = f[2] * invS;
        nf4.w = f[3] * invS;
        *(float4*)&nf_out[row * NR + r0] = nf4;
        if (j == 0) out[row] = dot * invS;
    }
}

extern "C" void kernel_launch(void* const* d_in, const int* in_sizes, int n_in,
                              void* d_out, int out_size, void* d_ws, size_t ws_size,
                              hipStream_t stream) {
    const float* x     = (const float*)d_in[0];
    const float* mu_g  = (const float*)d_in[1];
    const float* sig_g = (const float*)d_in[2];
    const float* ta    = (const float*)d_in[3];
    const float* tb    = (const float*)d_in[4];
    const float* tc    = (const float*)d_in[5];
    const float* td    = (const float*)d_in[6];
    const float* mfm   = (const float*)d_in[7];
    const float* tnw   = (const float*)d_in[8];
    const float* cons  = (const float*)d_in[9];
    const int*   ridx  = (const int*)d_in[10];

    const int nrows = in_sizes[0] / NF;            // 65536

    float* out     = (float*)d_out;
    float* nf_out  = out + nrows;
    float* mem_out = nf_out + (size_t)nrows * NR;

    const int grid = (nrows + ROWS_PER_BLOCK - 1) / ROWS_PER_BLOCK;
    anfis_kernel<<<grid, 256, 0, stream>>>(x, mu_g, sig_g, ta, tb, tc, td,
                                           mfm, tnw, cons, ridx,
                                           out, nf_out, mem_out, nrows);
}

// Round 2
// 106.345 us; speedup vs baseline: 1.1122x; 1.1122x over previous
//
#include <hip/hip_runtime.h>
#include <math.h>

#define NF 7
#define NR 128
#define RPB 8      // rows per iteration per block
#define ITERS 4    // row-chunks per block

__global__ __launch_bounds__(256) void anfis_kernel(
    const float* __restrict__ x,
    const float* __restrict__ mu_g,
    const float* __restrict__ sig_g,
    const float* __restrict__ ta, const float* __restrict__ tb,
    const float* __restrict__ tc, const float* __restrict__ td,
    const float* __restrict__ mf_mix,
    const float* __restrict__ tnw,
    const float* __restrict__ consequent,   // [128][8]
    const int*   __restrict__ rule_idx,     // [128][7]
    float* __restrict__ out,                // [B]
    float* __restrict__ nf_out,             // [B][128]
    float* __restrict__ mem_out,            // [B][14]
    int nrows)
{
    __shared__ float s_xaug[RPB][8];       // [1, x0..x6]
    __shared__ float s_mem[RPB][16];       // 14 used, padded
    __shared__ unsigned int s_mask32[32];  // 128 rule masks packed 4/word

    const int tid = threadIdx.x;
    const int row_local = tid >> 5;        // 0..7
    const int j = tid & 31;                // lane within row-group

    // ---- once per block: rule masks ----
    if (tid < NR) {
        int m = 0;
        #pragma unroll
        for (int i = 0; i < NF; ++i)
            if (rule_idx[tid * NF + i] != 0) m |= (1 << i);
        ((unsigned char*)s_mask32)[tid] = (unsigned char)m;
    }
    const float alpha = 1.0f / (1.0f + __expf(-mf_mix[0]));
    const float w     = 1.0f / (1.0f + __expf(-tnw[0]));

    // ---- once per block: row-invariant membership params (lanes j<14) ----
    float mu_j = 0.f, i2s2 = 0.f, q0 = 0.f, q1 = 0.f, q2 = 0.f, q3 = 0.f;
    float invL = 0.f, invR = 0.f;
    if (j < 14) {
        mu_j = mu_g[j];
        float sg = fmaxf(sig_g[j], 1e-6f);
        i2s2 = 1.0f / (2.0f * sg * sg);

        float p0 = ta[j], p1 = tb[j], p2 = tc[j], p3 = td[j];
        float lo, hi;
        lo = fminf(p0, p1); hi = fmaxf(p0, p1); p0 = lo; p1 = hi;
        lo = fminf(p2, p3); hi = fmaxf(p2, p3); p2 = lo; p3 = hi;
        lo = fminf(p0, p2); hi = fmaxf(p0, p2); p0 = lo; p2 = hi;
        lo = fminf(p1, p3); hi = fmaxf(p1, p3); p1 = lo; p3 = hi;
        lo = fminf(p1, p2); hi = fmaxf(p1, p2); p1 = lo; p2 = hi;
        q0 = p0; q1 = p1; q2 = p2; q3 = p3;
        invL = 1.0f / (p1 - p0 + 1e-6f);
        invR = 1.0f / (p3 - p2 + 1e-6f);
    }
    const float one_m_alpha = 1.0f - alpha;
    const float one_m_w     = 1.0f - w;

    const int base = blockIdx.x * (RPB * ITERS);
    const float4* __restrict__ cq = (const float4*)consequent;

    for (int it = 0; it < ITERS; ++it) {
        const int row = base + it * RPB + row_local;
        const bool live = (row < nrows);

        __syncthreads();   // protect s_xaug/s_mem reuse; makes masks visible on it==0

        // ---- stage x_aug ----
        if (j < NF) s_xaug[row_local][1 + j] = live ? x[row * NF + j] : 0.0f;
        if (j == NF) s_xaug[row_local][0] = 1.0f;

        // ---- membership (lanes j<14), row-variant part only ----
        if (j < 14) {
            const float xi = live ? x[row * NF + (j >> 1)] : 0.0f;
            const float dm = xi - mu_j;
            const float gauss = __expf(-(dm * dm) * i2s2);
            float left  = (xi - q0) * invL;
            left = fminf(fmaxf(left, 0.0f), 1.0f);
            const float flat = (xi >= q1 && xi <= q2) ? 1.0f : 0.0f;
            float right = (q3 - xi) * invR;
            right = fminf(fmaxf(right, 0.0f), 1.0f);
            const float trap = fmaxf(fminf(left, right), flat);
            const float m = fmaf(alpha, gauss, one_m_alpha * trap);
            s_mem[row_local][j] = m;
            if (live) mem_out[row * 14 + j] = m;
        }
        __syncthreads();

        // ---- 4 rules per thread ----
        const float4 xa0 = *(const float4*)&s_xaug[row_local][0];
        const float4 xa1 = *(const float4*)&s_xaug[row_local][4];
        const float4 mA = *(const float4*)&s_mem[row_local][0];
        const float4 mB = *(const float4*)&s_mem[row_local][4];
        const float4 mC = *(const float4*)&s_mem[row_local][8];
        const float  mD0 = s_mem[row_local][12];
        const float  mD1 = s_mem[row_local][13];

        float mlo[NF], mhi[NF];
        mlo[0] = mA.x; mhi[0] = mA.y;
        mlo[1] = mA.z; mhi[1] = mA.w;
        mlo[2] = mB.x; mhi[2] = mB.y;
        mlo[3] = mB.z; mhi[3] = mB.w;
        mlo[4] = mC.x; mhi[4] = mC.y;
        mlo[5] = mC.z; mhi[5] = mC.w;
        mlo[6] = mD0;  mhi[6] = mD1;

        const unsigned int pk = s_mask32[j];
        const int r0 = 4 * j;

        float f[4];
        float S = 0.0f, dot = 0.0f;

        #pragma unroll
        for (int k = 0; k < 4; ++k) {
            const unsigned int msk = (pk >> (8 * k)) & 0xffu;
            float g[NF];
            #pragma unroll
            for (int i = 0; i < NF; ++i)
                g[i] = ((msk >> i) & 1u) ? mhi[i] : mlo[i];

            const float prod = ((g[0] * g[1]) * (g[2] * g[3])) *
                               ((g[4] * g[5]) * g[6]);
            const float mn = fminf(fminf(fminf(g[0], g[1]), fminf(g[2], g[3])),
                                   fminf(fminf(g[4], g[5]), g[6]));
            const float fr = fmaf(w, prod, one_m_w * mn);

            const int r = r0 + k;
            const float4 c0 = cq[2 * r];
            const float4 c1 = cq[2 * r + 1];
            float ro = c0.x * xa0.x;
            ro = fmaf(c0.y, xa0.y, ro);
            ro = fmaf(c0.z, xa0.z, ro);
            ro = fmaf(c0.w, xa0.w, ro);
            ro = fmaf(c1.x, xa1.x, ro);
            ro = fmaf(c1.y, xa1.y, ro);
            ro = fmaf(c1.z, xa1.z, ro);
            ro = fmaf(c1.w, xa1.w, ro);

            f[k] = fr;
            S += fr;
            dot = fmaf(fr, ro, dot);
        }

        // ---- reduce over the 32-lane row-group ----
        #pragma unroll
        for (int off = 1; off < 32; off <<= 1) {
            S   += __shfl_xor(S, off, 64);
            dot += __shfl_xor(dot, off, 64);
        }
        const float invS = 1.0f / (S + 1e-8f);

        if (live) {
            float4 nf4;
            nf4.x = f[0] * invS;
            nf4.y = f[1] * invS;
            nf4.z = f[2] * invS;
            nf4.w = f[3] * invS;
            *(float4*)&nf_out[row * NR + r0] = nf4;
            if (j == 0) out[row] = dot * invS;
        }
    }
}

extern "C" void kernel_launch(void* const* d_in, const int* in_sizes, int n_in,
                              void* d_out, int out_size, void* d_ws, size_t ws_size,
                              hipStream_t stream) {
    const float* x     = (const float*)d_in[0];
    const float* mu_g  = (const float*)d_in[1];
    const float* sig_g = (const float*)d_in[2];
    const float* ta    = (const float*)d_in[3];
    const float* tb    = (const float*)d_in[4];
    const float* tc    = (const float*)d_in[5];
    const float* td    = (const float*)d_in[6];
    const float* mfm   = (const float*)d_in[7];
    const float* tnw   = (const float*)d_in[8];
    const float* cons  = (const float*)d_in[9];
    const int*   ridx  = (const int*)d_in[10];

    const int nrows = in_sizes[0] / NF;            // 65536

    float* out     = (float*)d_out;
    float* nf_out  = out + nrows;
    float* mem_out = nf_out + (size_t)nrows * NR;

    const int rows_per_block = RPB * ITERS;
    const int grid = (nrows + rows_per_block - 1) / rows_per_block;
    anfis_kernel<<<grid, 256, 0, stream>>>(x, mu_g, sig_g, ta, tb, tc, td,
                                           mfm, tnw, cons, ridx,
                                           out, nf_out, mem_out, nrows);
}